// Round 6
// baseline (45.042 us; speedup 1.0000x reference)
//
#include <hip/hip_runtime.h>
#include <hip/hip_fp16.h>

typedef _Float16 h2 __attribute__((ext_vector_type(2)));
typedef float f2 __attribute__((ext_vector_type(2)));

#define NCH   1024                 // chunks (one single-wave workgroup each)
#define CL    256                  // outputs per chunk
#define HALO  32                   // warm-up steps
#define SPB   8                    // steps per staged block
#define NB    ((HALO + CL) / SPB)  // 36 blocks
#define BH    (HALO / SPB)         // 4 halo blocks
#define DEPTH 6                    // staged blocks in flight
#define UBUF_DW (SPB * 140)        // 1120 dwords per block
#define TROW  141                  // traj row stride (odd -> conflict-free)
#define NROWS 16                   // pair-rows per phase-B round (32 steps)

#if __has_builtin(__builtin_amdgcn_exp2f)
#define EXP2F __builtin_amdgcn_exp2f
#else
#define EXP2F exp2f
#endif
#if __has_builtin(__builtin_amdgcn_rcpf)
#define RCPF __builtin_amdgcn_rcpf
#else
#define RCPF(x) (1.0f / (x))
#endif

#define A_K   (-14.4269504088896341f)   /* -10*log2(e) */
#define UPC_K (7.21347520444481704f)    /* -A_K*0.5    */
#define K2_K  (2.8853900817779268f)     /* 2*log2(e)   */

__device__ __forceinline__ h2 pkrtz(float a, float b) {
    return __builtin_bit_cast(h2, __builtin_amdgcn_cvt_pkrtz(a, b));
}
__device__ __forceinline__ float sigstep(float w, float up) {
    return RCPF(1.0f + EXP2F(__builtin_fmaf(A_K, w, up)));
}
__device__ __forceinline__ float fold(float u) {
    return __builtin_fmaf(A_K, u, UPC_K);
}
__device__ __forceinline__ uint32_t pk16(float a, float b) {
    return __builtin_bit_cast(uint32_t, pkrtz(a, b));
}
__device__ __forceinline__ h2 ldw(uint32_t v) {
    return __builtin_bit_cast(h2, v);
}
__device__ __forceinline__ h2 tanh2(h2 a) {
    float z0 = (float)a[0], z1 = (float)a[1];
    float t0 = 1.0f - 2.0f * RCPF(1.0f + EXP2F(K2_K * z0));
    float t1 = 1.0f - 2.0f * RCPF(1.0f + EXP2F(K2_K * z1));
    return pkrtz(t0, t1);
}

__device__ __forceinline__ void gload_lds16(const float* g, float* l) {
    __builtin_amdgcn_global_load_lds(
        (__attribute__((address_space(1))) void*)(void*)g,
        (__attribute__((address_space(3))) void*)(void*)l, 16, 0, 0);
}
__device__ __forceinline__ void gload_lds4(const float* g, float* l) {
    __builtin_amdgcn_global_load_lds(
        (__attribute__((address_space(1))) void*)(void*)g,
        (__attribute__((address_space(3))) void*)(void*)l, 4, 0, 0);
}

#define STR2(x) #x
#define WAITVMn(N) asm volatile("s_waitcnt vmcnt(" STR2(N) ")" ::: "memory")
#define WAITLGKM   asm volatile("s_waitcnt lgkmcnt(0)" ::: "memory")

__global__ void __launch_bounds__(64)
fastnet_kernel(const float* __restrict__ x, const float* __restrict__ u,
               const float* __restrict__ W1, const float* __restrict__ W2,
               const float* __restrict__ W3, float* __restrict__ out) {
    // 26.25 KB u 6-deep + 8.8 KB traj + 1.125 KB x = 36.2 KB -> 4 wg/CU (grid resident)
    __shared__ __align__(16) float    ubuf_s[DEPTH * UBUF_DW];
    __shared__ __align__(16) uint32_t traj[NROWS * TROW];
    __shared__ __align__(16) float    xbuf_s[3 * 96];

    const int  lane  = threadIdx.x;
    const int  ch    = blockIdx.x;
    const long cbase = (long)ch * CL;
    const float* su  = u + (cbase - (long)HALO) * 140;
    float* ubuf0 = ubuf_s;
    float* xbuf0 = xbuf_s;

    // ---- initial weights: chunk 0 exact, others converge through the halo ----
    float wa, wb, wc;
    if (ch == 0) {
        wa = (lane < 30) ? W1[lane] : (lane < 130 ? W2[lane - 30] : W3[lane - 130]);
        wb = W2[lane + 34];
        int kc = lane + 128;
        wc = (lane < 12) ? ((kc < 130) ? W2[kc - 30] : W3[kc - 130]) : 0.5f;
    } else {
        wa = wb = wc = 0.5f;
    }

    // stage u-block B_ (6 vmcnt events) (+1 x event when B_ starts a phase-B round)
#define STAGE(B_) do {                                                          \
        const float* s_ = su + (long)(B_) * UBUF_DW;                            \
        float* d_ = ubuf0 + ((B_) % DEPTH) * UBUF_DW;                           \
        _Pragma("unroll")                                                       \
        for (int i_ = 0; i_ < 4; i_++)                                          \
            gload_lds16(s_ + i_ * 256 + lane * 4, d_ + i_ * 256);               \
        gload_lds4(s_ + 1024 + lane, d_ + 1024);                                \
        if (lane < 32) gload_lds4(s_ + 1088 + lane, d_ + 1088);                 \
        if ((B_) >= BH && (((B_) - BH) & 3) == 0) {                             \
            int r_ = ((B_) - BH) >> 2;                                          \
            if (lane < 24)                                                      \
                gload_lds16(x + (cbase + r_ * 32) * 3 + lane * 4,               \
                            xbuf0 + (r_ % 3) * 96 + lane * 4);                  \
        }                                                                       \
    } while (0)

    // one 8-step iteration. NW_: literal vmcnt; POS_: block pos in round (0..3);
    // TRAJ_: write trajectory; PB_: run phase-B MLP; STG_: issue next stage.
#define ITER(B_, NW_, POS_, TRAJ_, PB_, STG_) do {                              \
        WAITVMn(NW_);                                                           \
        const float* ub_ = ubuf0 + ((B_) % DEPTH) * UBUF_DW;                    \
        float uu0[SPB], uu1[SPB], uu2[SPB];                                     \
        _Pragma("unroll")                                                       \
        for (int t = 0; t < SPB; t++) {                                         \
            uu0[t] = ub_[t * 140 + lane];                                       \
            uu1[t] = ub_[t * 140 + 64 + lane];                                  \
            uu2[t] = ub_[t * 140 + 128 + (lane < 12 ? lane : 11)];              \
        }                                                                       \
        WAITLGKM;                      /* reads retired -> buffer reusable */   \
        if (STG_) STAGE((B_) + DEPTH);                                          \
        _Pragma("unroll")                                                       \
        for (int t = 0; t < SPB; t += 2) {                                      \
            wa = sigstep(wa, fold(uu0[t]));                                     \
            wb = sigstep(wb, fold(uu1[t]));                                     \
            wc = sigstep(wc, fold(uu2[t]));                                     \
            float wa0 = wa, wb0 = wb, wc0 = wc;                                 \
            wa = sigstep(wa, fold(uu0[t + 1]));                                 \
            wb = sigstep(wb, fold(uu1[t + 1]));                                 \
            wc = sigstep(wc, fold(uu2[t + 1]));                                 \
            if (TRAJ_) {                                                        \
                uint32_t* tw = &traj[((POS_) * 4 + (t >> 1)) * TROW + lane];    \
                tw[0]  = pk16(wa0, wa);                                         \
                tw[64] = pk16(wb0, wb);                                         \
                if (lane < 12) tw[128] = pk16(wc0, wc);                         \
            }                                                                   \
        }                                                                       \
        if (PB_ && lane < NROWS) {                                              \
            int r_ = ((B_) - (BH + 3)) >> 2;                                    \
            const float* xb_ = xbuf0 + (r_ % 3) * 96 + 6 * lane;                \
            f2 v0 = *(const f2*)(xb_);                                          \
            f2 v1 = *(const f2*)(xb_ + 2);                                      \
            f2 v2 = *(const f2*)(xb_ + 4);                                      \
            h2 xq0 = pkrtz(v0[0], v1[1]);                                       \
            h2 xq1 = pkrtz(v0[1], v2[0]);                                       \
            h2 xq2 = pkrtz(v1[0], v2[1]);                                       \
            const uint32_t* tr_ = &traj[lane * TROW];                           \
            h2 h1[10];                                                          \
            _Pragma("unroll")                                                   \
            for (int cc = 0; cc < 10; cc++) {                                   \
                h2 acc = ldw(tr_[cc]) * xq0;                                    \
                acc += ldw(tr_[10 + cc]) * xq1;                                 \
                acc += ldw(tr_[20 + cc]) * xq2;                                 \
                h1[cc] = tanh2(acc);                                            \
            }                                                                   \
            h2 hh[10];                                                          \
            _Pragma("unroll")                                                   \
            for (int cc = 0; cc < 10; cc++) {                                   \
                h2 acc = h1[0] * ldw(tr_[30 + cc]);                             \
                _Pragma("unroll")                                               \
                for (int r2 = 1; r2 < 10; r2++)                                 \
                    acc += h1[r2] * ldw(tr_[30 + r2 * 10 + cc]);                \
                hh[cc] = tanh2(acc);                                            \
            }                                                                   \
            h2 ya = hh[0] * ldw(tr_[130]);                                      \
            _Pragma("unroll")                                                   \
            for (int r2 = 1; r2 < 10; r2++) ya += hh[r2] * ldw(tr_[130 + r2]);  \
            long g0_ = cbase + r_ * 32 + 2 * lane;                              \
            f2 o_; o_[0] = (float)ya[0]; o_[1] = (float)ya[1];                  \
            *reinterpret_cast<f2*>(out + g0_) = o_;                             \
        }                                                                       \
    } while (0)

    // ---- prologue: fill the 6-deep pipeline ----
    const int b0 = (ch == 0) ? BH : 0;
    for (int i = 0; i < DEPTH; i++) STAGE(b0 + i);

    // ---- halo round (skipped for chunk 0, which starts exactly at block BH) ----
    if (ch != 0) {
        ITER(0, 31, 0, 0, 0, 1);
        ITER(1, 31, 1, 0, 0, 1);
        ITER(2, 31, 2, 0, 0, 1);
        ITER(3, 32, 3, 0, 0, 1);
    }

    // ---- main rounds: blocks 4..27 (6 rounds), uniform counted waits ----
    for (int rb = BH; rb <= 24; rb += 4) {
        ITER(rb + 0, 31, 0, 1, 0, 1);
        ITER(rb + 1, 31, 1, 1, 0, 1);
        ITER(rb + 2, 31, 2, 1, 0, 1);
        ITER(rb + 3, 32, 3, 1, 1, 1);
    }

    // ---- epilogue: blocks 28..35, draining waits (ledger-derived) ----
    ITER(28, 31, 0, 1, 0, 1);   // stages block 34
    ITER(29, 31, 1, 1, 0, 1);   // stages block 35 (last)
    ITER(30, 31, 2, 1, 0, 0);
    ITER(31, 25, 3, 1, 1, 0);
    ITER(32, 18, 0, 1, 0, 0);
    ITER(33, 12, 1, 1, 0, 0);
    ITER(34,  6, 2, 1, 0, 0);
    ITER(35,  0, 3, 1, 1, 0);

#undef STAGE
#undef ITER
}

extern "C" void kernel_launch(void* const* d_in, const int* in_sizes, int n_in,
                              void* d_out, int out_size, void* d_ws, size_t ws_size,
                              hipStream_t stream) {
    const float* x  = (const float*)d_in[0];
    const float* u  = (const float*)d_in[1];
    const float* W1 = (const float*)d_in[2];
    const float* W2 = (const float*)d_in[3];
    const float* W3 = (const float*)d_in[4];
    float* out = (float*)d_out;

    hipLaunchKernelGGL(fastnet_kernel, dim3(NCH), dim3(64), 0, stream,
                       x, u, W1, W2, W3, out);
}